// Round 7
// baseline (51814.380 us; speedup 1.0000x reference)
//
#include <hip/hip_runtime.h>

#define TT 512
#define BB 256
#define DD 128
#define HH 256
#define NWG 16        // one WG per 16 batch rows; fully independent -> no global sync
#define NTHR 512      // 8 waves
#define EPSF 1e-5f

typedef __attribute__((ext_vector_type(8))) short short8;   // 8 bf16 (4 VGPRs) MFMA frag
typedef __attribute__((ext_vector_type(4))) short short4v;  // 4 bf16 (8B)
typedef __attribute__((ext_vector_type(4))) float f32x4;    // MFMA accumulator

// ws weight layout (bytes): fragment-ordered hi/lo bf16 tiles, 2KB per 16x32 tile
#define WOFF_I0 0u
#define WOFF_H0 (256u*1024)
#define WOFF_W0 (768u*1024)
#define WOFF_U0 (896u*1024)
#define WOFF_I1 (1152u*1024)
#define WOFF_H1 (1664u*1024)
#define WOFF_W1 (2176u*1024)
#define WOFF_U1 (2432u*1024)
// total 2688 KB < ws_size

__device__ __forceinline__ unsigned short rneb(float f) {       // f32 -> bf16 RNE
  unsigned u = __float_as_uint(f);
  return (unsigned short)((u + 0x7FFFu + ((u >> 16) & 1u)) >> 16);
}
__device__ __forceinline__ float b2f(unsigned short h) {
  return __uint_as_float(((unsigned)h) << 16);
}
__device__ __forceinline__ float sigmf(float x) { return 1.f / (1.f + __expf(-x)); }

// ---------- prep: f32 weights -> {hi,lo} bf16 in MFMA-B-fragment order ----------
// tile(ct,kt) of W[N][K]: 2KB = 1KB hi + 1KB lo; lane l holds col=ct*16+(l&15),
// k = kt*32 + (l>>4)*8 + j (j=0..7, memory-contiguous).
extern "C" __global__ void prep_w(const float* __restrict__ src, char* __restrict__ dst,
                                  int N, int K) {
  int idx = blockIdx.x * 256 + threadIdx.x;
  if (idx >= N * K) return;
  int n = idx / K, k = idx - n * K;
  float w = src[idx];
  unsigned short hi = rneb(w);
  unsigned short lo = rneb(w - b2f(hi));
  int nkt = K >> 5;
  size_t off = (size_t)((n >> 4) * nkt + (k >> 5)) * 2048
             + (size_t)((n & 15) + (((k >> 3) & 3) << 4)) * 16 + (k & 7) * 2;
  *(unsigned short*)(dst + off) = hi;
  *(unsigned short*)(dst + off + 1024) = lo;
}

// ---------- compensated MFMA GEMM: C(16 x NTC*16) = A(16 x NKT*32) * W^T + bias ----------
template<int NKT, int NTC>
__device__ __forceinline__ void gemm16(const char* __restrict__ wmat,
                                       const char* fhi, const char* flo,
                                       const float* __restrict__ bias,
                                       float* P, int sp, int lane, int wave) {
  short8 ahi[NKT], alo[NKT];
  #pragma unroll
  for (int kt = 0; kt < NKT; ++kt) {
    ahi[kt] = *(const short8*)(fhi + (kt * 64 + lane) * 16);
    alo[kt] = *(const short8*)(flo + (kt * 64 + lane) * 16);
  }
  const int colr = lane & 15, rb = (lane >> 4) << 2;
  #pragma unroll
  for (int ci = 0; ci < NTC / 8; ci += 2) {   // 2-way ct unroll: 2 indep acc chains
    const int ct0 = wave + ci * 8, ct1 = ct0 + 8;
    const char* bp0 = wmat + (size_t)(ct0 * NKT) * 2048 + lane * 16;
    const char* bp1 = wmat + (size_t)(ct1 * NKT) * 2048 + lane * 16;
    f32x4 acc0 = {0.f, 0.f, 0.f, 0.f}, acc1 = {0.f, 0.f, 0.f, 0.f};
    #pragma unroll
    for (int kt = 0; kt < NKT; ++kt) {
      short8 bh0 = *(const short8*)(bp0 + kt * 2048);
      short8 bl0 = *(const short8*)(bp0 + kt * 2048 + 1024);
      short8 bh1 = *(const short8*)(bp1 + kt * 2048);
      short8 bl1 = *(const short8*)(bp1 + kt * 2048 + 1024);
      acc0 = __builtin_amdgcn_mfma_f32_16x16x32_bf16(ahi[kt], bh0, acc0, 0, 0, 0);
      acc1 = __builtin_amdgcn_mfma_f32_16x16x32_bf16(ahi[kt], bh1, acc1, 0, 0, 0);
      acc0 = __builtin_amdgcn_mfma_f32_16x16x32_bf16(ahi[kt], bl0, acc0, 0, 0, 0);
      acc1 = __builtin_amdgcn_mfma_f32_16x16x32_bf16(ahi[kt], bl1, acc1, 0, 0, 0);
      acc0 = __builtin_amdgcn_mfma_f32_16x16x32_bf16(alo[kt], bh0, acc0, 0, 0, 0);
      acc1 = __builtin_amdgcn_mfma_f32_16x16x32_bf16(alo[kt], bh1, acc1, 0, 0, 0);
    }
    const int c0 = ct0 * 16 + colr, c1 = ct1 * 16 + colr;
    const float bb0 = bias[c0], bb1 = bias[c1];
    #pragma unroll
    for (int i = 0; i < 4; ++i) {   // C/D: col=lane&15, row=(lane>>4)*4+i (m89/m91)
      P[(rb + i) * sp + c0] = acc0[i] + bb0;
      P[(rb + i) * sp + c1] = acc1[i] + bb1;
    }
  }
}

// build A-frags (hi/lo) from h in LDS (f32 [16][260]), K=256 -> 8 kt tiles
__device__ __forceinline__ void buildHfrag(char* dhi, char* dlo, const float* hsrc, int tid) {
  int kt = tid >> 6, l = tid & 63;
  int r_ = l & 15, k0 = kt * 32 + (l >> 4) * 8;
  const float* hp = &hsrc[r_ * 260 + k0];
  float4 va = *(const float4*)hp;
  float4 vb = *(const float4*)(hp + 4);
  float vv[8] = {va.x, va.y, va.z, va.w, vb.x, vb.y, vb.z, vb.w};
  unsigned short hh[8], ll[8];
  #pragma unroll
  for (int q = 0; q < 8; ++q) { hh[q] = rneb(vv[q]); ll[q] = rneb(vv[q] - b2f(hh[q])); }
  union { unsigned short u[8]; short8 v; } ph, pl;
  #pragma unroll
  for (int q = 0; q < 8; ++q) { ph.u[q] = hh[q]; pl.u[q] = ll[q]; }
  *(short8*)(dhi + (kt * 64 + l) * 16) = ph.v;
  *(short8*)(dlo + (kt * 64 + l) * 16) = pl.v;
}

__device__ __forceinline__ void lnstats(const float* P, int sp, int row, int seg,
                                        int ncol, float& m, float& r) {
  float s = 0.f, ss = 0.f;
  for (int c = seg; c < ncol; c += 32) { float v = P[row * sp + c]; s += v; ss += v * v; }
  #pragma unroll
  for (int off = 16; off; off >>= 1) { s += __shfl_xor(s, off); ss += __shfl_xor(ss, off); }
  float inv = 1.f / (float)ncol;
  m = s * inv;
  r = rsqrtf(ss * inv - m * m + EPSF);
}

extern "C" __global__ void __launch_bounds__(NTHR, 2)
gru_main(const float* __restrict__ input, const int* __restrict__ seqlens,
         const float* __restrict__ bi0, const float* __restrict__ bh0,
         const float* __restrict__ bw0, const float* __restrict__ bu0,
         const float* __restrict__ bi1, const float* __restrict__ bh1,
         const float* __restrict__ bw1, const float* __restrict__ bu1,
         const char* __restrict__ wsw, float* __restrict__ out)
{
  extern __shared__ char lds[];
  char* FXHI = lds;                      // 8KB (up to 8 kt)
  char* FXLO = lds + 8192;
  char* FHHI = lds + 16384;
  char* FHLO = lds + 24576;
  float* h0 = (float*)(lds + 32768);     // [16][260] f32, pad stride
  float* h1 = (float*)(lds + 49408);
  float* P0 = (float*)(lds + 66048);     // [16][520] f32 (also viewed stride 264)
  float* P1 = (float*)(lds + 99328);
  int* slv  = (int*)(lds + 132608);

  const int tid = threadIdx.x, lane = tid & 63, wave = tid >> 6;
  const int b0 = blockIdx.x * 16;

  for (int i = tid; i < 16 * 260; i += NTHR) { h0[i] = 0.f; h1[i] = 0.f; }
  if (tid < 16) slv[tid] = seqlens[b0 + tid];
  __syncthreads();

  const size_t YSZ = (size_t)TT * BB * HH;
  const int row = tid >> 5, seg = tid & 31, j0 = seg * 8;

  for (int t = 0; t < TT; ++t) {
    // ---- frag build: X <- input[t] (K=128, 4 kt), H <- h0 (K=256, 8 kt)
    {
      int kt = tid >> 7, l = (tid >> 1) & 63, jj0 = (tid & 1) * 4;
      int r_ = l & 15, k0 = kt * 32 + (l >> 4) * 8 + jj0;
      float4 v = *(const float4*)&input[((size_t)t * BB + b0 + r_) * DD + k0];
      float vv[4] = {v.x, v.y, v.z, v.w};
      union { unsigned short u[4]; short4v s; } ph, pl;
      #pragma unroll
      for (int q = 0; q < 4; ++q) {
        ph.u[q] = rneb(vv[q]);
        pl.u[q] = rneb(vv[q] - b2f(ph.u[q]));
      }
      *(short4v*)(FXHI + (kt * 64 + l) * 16 + jj0 * 2) = ph.s;
      *(short4v*)(FXLO + (kt * 64 + l) * 16 + jj0 * 2) = pl.s;
    }
    buildHfrag(FHHI, FHLO, h0, tid);
    __syncthreads();

    // ================= LAYER 0 =================
    gemm16<4, 32>(wsw + WOFF_I0, FXHI, FXLO, bi0, P0, 520, lane, wave);
    gemm16<8, 32>(wsw + WOFF_H0, FHHI, FHLO, bh0, P1, 520, lane, wave);
    __syncthreads();
    float m1, r1, m2, r2;
    lnstats(P0, 520, row, seg, 512, m1, r1);
    lnstats(P1, 520, row, seg, 512, m2, r2);
    float zv[8], rv[8];
    {
      float4 xa = *(const float4*)&P0[row * 520 + j0];
      float4 xb = *(const float4*)&P0[row * 520 + j0 + 4];
      float4 xc = *(const float4*)&P0[row * 520 + 256 + j0];
      float4 xd = *(const float4*)&P0[row * 520 + 256 + j0 + 4];
      float4 ha = *(const float4*)&P1[row * 520 + j0];
      float4 hb = *(const float4*)&P1[row * 520 + j0 + 4];
      float4 hc = *(const float4*)&P1[row * 520 + 256 + j0];
      float4 hd = *(const float4*)&P1[row * 520 + 256 + j0 + 4];
      float xz[8] = {xa.x,xa.y,xa.z,xa.w,xb.x,xb.y,xb.z,xb.w};
      float xr[8] = {xc.x,xc.y,xc.z,xc.w,xd.x,xd.y,xd.z,xd.w};
      float hz[8] = {ha.x,ha.y,ha.z,ha.w,hb.x,hb.y,hb.z,hb.w};
      float hr[8] = {hc.x,hc.y,hc.z,hc.w,hd.x,hd.y,hd.z,hd.w};
      #pragma unroll
      for (int q = 0; q < 8; ++q) {
        zv[q] = sigmf((xz[q] - m1) * r1 + (hz[q] - m2) * r2);
        rv[q] = sigmf((xr[q] - m1) * r1 + (hr[q] - m2) * r2);
      }
    }
    __syncthreads();   // release P before reuse
    gemm16<4, 16>(wsw + WOFF_W0, FXHI, FXLO, bw0, P0, 264, lane, wave);
    gemm16<8, 16>(wsw + WOFF_U0, FHHI, FHLO, bu0, P1, 264, lane, wave);
    __syncthreads();
    float m3, r3, m4, r4;
    lnstats(P0, 264, row, seg, 256, m3, r3);
    lnstats(P1, 264, row, seg, 256, m4, r4);
    int sl_ = slv[row];
    float hn0[8];
    {
      float4 wa = *(const float4*)&P0[row * 264 + j0];
      float4 wb = *(const float4*)&P0[row * 264 + j0 + 4];
      float4 ua = *(const float4*)&P1[row * 264 + j0];
      float4 ub = *(const float4*)&P1[row * 264 + j0 + 4];
      float4 hpa = *(const float4*)&h0[row * 260 + j0];
      float4 hpb = *(const float4*)&h0[row * 260 + j0 + 4];
      float pw[8] = {wa.x,wa.y,wa.z,wa.w,wb.x,wb.y,wb.z,wb.w};
      float pu[8] = {ua.x,ua.y,ua.z,ua.w,ub.x,ub.y,ub.z,ub.w};
      float hp[8] = {hpa.x,hpa.y,hpa.z,hpa.w,hpb.x,hpb.y,hpb.z,hpb.w};
      #pragma unroll
      for (int q = 0; q < 8; ++q) {
        float hh = tanhf((pw[q] - m3) * r3 + rv[q] * ((pu[q] - m4) * r4));
        float x = (1.f - zv[q]) * hp[q] + zv[q] * hh;
        hn0[q] = (t < sl_) ? x : 0.f;
      }
    }
    {
      float4 w0 = {hn0[0], hn0[1], hn0[2], hn0[3]};
      float4 w1 = {hn0[4], hn0[5], hn0[6], hn0[7]};
      *(float4*)&h0[row * 260 + j0] = w0;
      *(float4*)&h0[row * 260 + j0 + 4] = w1;
      if (t == sl_ - 1) {
        // hy layout is (L, B, H): layer 0 at offset (0*BB + b)*HH
        float* hy = out + YSZ + (size_t)(b0 + row) * HH + j0;
        *(float4*)hy = w0; *(float4*)(hy + 4) = w1;
      }
    }
    __syncthreads();

    // ================= LAYER 1 (x = h0 new) =================
    buildHfrag(FXHI, FXLO, h0, tid);
    buildHfrag(FHHI, FHLO, h1, tid);
    __syncthreads();
    gemm16<8, 32>(wsw + WOFF_I1, FXHI, FXLO, bi1, P0, 520, lane, wave);
    gemm16<8, 32>(wsw + WOFF_H1, FHHI, FHLO, bh1, P1, 520, lane, wave);
    __syncthreads();
    lnstats(P0, 520, row, seg, 512, m1, r1);
    lnstats(P1, 520, row, seg, 512, m2, r2);
    {
      float4 xa = *(const float4*)&P0[row * 520 + j0];
      float4 xb = *(const float4*)&P0[row * 520 + j0 + 4];
      float4 xc = *(const float4*)&P0[row * 520 + 256 + j0];
      float4 xd = *(const float4*)&P0[row * 520 + 256 + j0 + 4];
      float4 ha = *(const float4*)&P1[row * 520 + j0];
      float4 hb = *(const float4*)&P1[row * 520 + j0 + 4];
      float4 hc = *(const float4*)&P1[row * 520 + 256 + j0];
      float4 hd = *(const float4*)&P1[row * 520 + 256 + j0 + 4];
      float xz[8] = {xa.x,xa.y,xa.z,xa.w,xb.x,xb.y,xb.z,xb.w};
      float xr[8] = {xc.x,xc.y,xc.z,xc.w,xd.x,xd.y,xd.z,xd.w};
      float hz[8] = {ha.x,ha.y,ha.z,ha.w,hb.x,hb.y,hb.z,hb.w};
      float hr[8] = {hc.x,hc.y,hc.z,hc.w,hd.x,hd.y,hd.z,hd.w};
      #pragma unroll
      for (int q = 0; q < 8; ++q) {
        zv[q] = sigmf((xz[q] - m1) * r1 + (hz[q] - m2) * r2);
        rv[q] = sigmf((xr[q] - m1) * r1 + (hr[q] - m2) * r2);
      }
    }
    __syncthreads();
    gemm16<8, 16>(wsw + WOFF_W1, FXHI, FXLO, bw1, P0, 264, lane, wave);
    gemm16<8, 16>(wsw + WOFF_U1, FHHI, FHLO, bu1, P1, 264, lane, wave);
    __syncthreads();
    lnstats(P0, 264, row, seg, 256, m3, r3);
    lnstats(P1, 264, row, seg, 256, m4, r4);
    float hn1[8];
    {
      float4 wa = *(const float4*)&P0[row * 264 + j0];
      float4 wb = *(const float4*)&P0[row * 264 + j0 + 4];
      float4 ua = *(const float4*)&P1[row * 264 + j0];
      float4 ub = *(const float4*)&P1[row * 264 + j0 + 4];
      float4 hpa = *(const float4*)&h1[row * 260 + j0];
      float4 hpb = *(const float4*)&h1[row * 260 + j0 + 4];
      float pw[8] = {wa.x,wa.y,wa.z,wa.w,wb.x,wb.y,wb.z,wb.w};
      float pu[8] = {ua.x,ua.y,ua.z,ua.w,ub.x,ub.y,ub.z,ub.w};
      float hp[8] = {hpa.x,hpa.y,hpa.z,hpa.w,hpb.x,hpb.y,hpb.z,hpb.w};
      #pragma unroll
      for (int q = 0; q < 8; ++q) {
        float hh = tanhf((pw[q] - m3) * r3 + rv[q] * ((pu[q] - m4) * r4));
        float x = (1.f - zv[q]) * hp[q] + zv[q] * hh;
        hn1[q] = (t < sl_) ? x : 0.f;
      }
    }
    {
      float4 w0 = {hn1[0], hn1[1], hn1[2], hn1[3]};
      float4 w1 = {hn1[4], hn1[5], hn1[6], hn1[7]};
      *(float4*)&h1[row * 260 + j0] = w0;
      *(float4*)&h1[row * 260 + j0 + 4] = w1;
      float* y = out + ((size_t)t * BB + b0 + row) * HH + j0;
      *(float4*)y = w0; *(float4*)(y + 4) = w1;
      if (t == sl_ - 1) {
        // hy layout is (L, B, H): layer 1 at offset (1*BB + b)*HH
        float* hy = out + YSZ + (size_t)(BB + b0 + row) * HH + j0;
        *(float4*)hy = w0; *(float4*)(hy + 4) = w1;
      }
    }
    __syncthreads();
  }
}

extern "C" void kernel_launch(void* const* d_in, const int* in_sizes, int n_in,
                              void* d_out, int out_size, void* d_ws, size_t ws_size,
                              hipStream_t stream) {
  const float* input   = (const float*)d_in[0];
  const int*   seqlens = (const int*)d_in[1];
  const float* Wm[8] = {(const float*)d_in[2],  (const float*)d_in[4],
                        (const float*)d_in[6],  (const float*)d_in[8],
                        (const float*)d_in[10], (const float*)d_in[12],
                        (const float*)d_in[14], (const float*)d_in[16]};
  const float* bi0 = (const float*)d_in[3];  const float* bh0 = (const float*)d_in[5];
  const float* bw0 = (const float*)d_in[7];  const float* bu0 = (const float*)d_in[9];
  const float* bi1 = (const float*)d_in[11]; const float* bh1 = (const float*)d_in[13];
  const float* bw1 = (const float*)d_in[15]; const float* bu1 = (const float*)d_in[17];
  float* out = (float*)d_out;
  char*  wsw = (char*)d_ws;

  const unsigned offs[8] = {WOFF_I0, WOFF_H0, WOFF_W0, WOFF_U0,
                            WOFF_I1, WOFF_H1, WOFF_W1, WOFF_U1};
  const int Ns[8] = {512, 512, 256, 256, 512, 512, 256, 256};
  const int Ks[8] = {128, 256, 128, 256, 256, 256, 256, 256};
  for (int i = 0; i < 8; ++i) {
    int n = Ns[i] * Ks[i];
    hipLaunchKernelGGL(prep_w, dim3((n + 255) / 256), dim3(256), 0, stream,
                       Wm[i], wsw + offs[i], Ns[i], Ks[i]);
  }

  hipFuncSetAttribute((const void*)gru_main,
                      hipFuncAttributeMaxDynamicSharedMemorySize, 135168);
  hipLaunchKernelGGL(gru_main, dim3(NWG), dim3(NTHR), 132672, stream,
                     input, seqlens,
                     bi0, bh0, bw0, bu0, bi1, bh1, bw1, bu1,
                     (const char*)wsw, out);
}